// Round 1
// 336.696 us; speedup vs baseline: 1.0324x; 1.0324x over previous
//
#include <hip/hip_runtime.h>
#include <cstdint>
#include <cstddef>

// B=4, S=2048, D=1024, U=1024 self-attention, fp32 in/out.
// R8: QK-proj + scores GEMMs ported to 256x256-tile, BK=64, 8-wave, 4-phase
//     schedule with counted vmcnt(6) (loads stay in flight across barriers),
//     k-half-major swizzled LDS, raw s_barrier, setprio around MFMA clusters.
//     V-proj / PV stay on the 128x128 2-barrier kernel (their 256^2 grids
//     would be 128 blocks = half the CUs idle).

typedef unsigned short ushort_t;
typedef _Float16 half_t;
typedef __attribute__((ext_vector_type(8))) short short8;
typedef __attribute__((ext_vector_type(4))) float floatx4;

__device__ inline unsigned short h2u(half_t h) {
  union { half_t h; unsigned short u; } v; v.h = h; return v.u;
}

// async 16B global -> LDS (DMA). LDS dest = wave-uniform base + lane*16 (HW).
__device__ __forceinline__ void gload16(const half_t* g, half_t* l) {
  __builtin_amdgcn_global_load_lds(
      (const __attribute__((address_space(1))) unsigned int*)g,
      (__attribute__((address_space(3))) unsigned int*)l, 16, 0, 0);
}

#define BAR() asm volatile("s_barrier" ::: "memory")
#define LGKM0() asm volatile("s_waitcnt lgkmcnt(0)" ::: "memory")
#define VM6() asm volatile("s_waitcnt vmcnt(6)" ::: "memory")
#define VM0() asm volatile("s_waitcnt vmcnt(0)" ::: "memory")

// ---------- constants ----------
#define MX 8192       // B*S
#define KCAT 2048     // 2*D (fp16 2-term split-concatenated K dim)

// ws byte offsets (regions reused across phases; S overwrites xcat/wt)
#define XCAT_OFF 0UL                  // half [8192][2048] = 33554432 B
#define WT_OFF   50331648UL           // half 3 x [1024][2048] = 12582912 B
#define S_OFF    0UL                  // float [4][2048][2048] = 67108864 B
#define QCAT_OFF 69206016UL           // half [8192][2048]
#define KCAT_OFF 119537664UL          // half [8192][2048]
#define VT_OFF   169869312UL          // half [4][1024][2048] = 16777216 B
#define WS_NEED  186646528UL

// ---------- K1a: split inputs X -> Xcat = [xh | xl] (fp16) ----------
__global__ __launch_bounds__(256) void k_split_x(const float* __restrict__ X,
                                                 half_t* __restrict__ xcat) {
  long long i = (long long)blockIdx.x * 256 + threadIdx.x;  // over 8192*1024
  float x = X[i];
  half_t h = (half_t)x;
  half_t lo = (half_t)(x - (float)h);
  long long row = i >> 10;
  int col = (int)(i & 1023);
  half_t* r = xcat + row * KCAT;
  r[col] = h;
  r[col + 1024] = lo;
}

// ---------- K1b: transpose W -> WT_cat = [Wh | Wh] per weight ----------
__global__ __launch_bounds__(256) void k_split_wt(const float* __restrict__ Wq,
                                                  const float* __restrict__ Wk,
                                                  const float* __restrict__ Wv,
                                                  half_t* __restrict__ wt) {
  __shared__ float tile[64][65];
  const float* W = (blockIdx.z == 0) ? Wq : ((blockIdx.z == 1) ? Wk : Wv);
  half_t* out = wt + (size_t)blockIdx.z * 1024 * KCAT;
  int d0 = blockIdx.y * 64, u0 = blockIdx.x * 64;
  int t = threadIdx.x;
  int tr = t >> 6, tc = t & 63;
  for (int r = 0; r < 64; r += 4)
    tile[r + tr][tc] = W[(size_t)(d0 + r + tr) * 1024 + (u0 + tc)];
  __syncthreads();
  for (int r = 0; r < 64; r += 4) {
    int urow = r + tr, dcol = tc;
    float x = tile[dcol][urow];  // = WT[u0+urow][d0+dcol]
    half_t h = (half_t)x;
    half_t* o = out + (size_t)(u0 + urow) * KCAT + d0;
    o[dcol] = h;
    o[dcol + 1024] = h;
  }
}

enum { EP_F32 = 0, EP_QK = 1, EP_VT = 2 };

// ---------- old 128x128 GEMM (kept for V-proj EP_VT and PV EP_F32) ----------
template <int MODE>
__global__ __launch_bounds__(256, 4) void k_gemm(
    const half_t* __restrict__ A, long long aBatch, int lda,
    const half_t* __restrict__ Bt, long long bBatch, int ldb,
    void* __restrict__ Cout, long long cBatch, int ldc, int K,
    half_t* __restrict__ CoutK) {
  __shared__ __align__(16) half_t As[128 * 64];
  __shared__ __align__(16) half_t Bs[128 * 64];
  const int t = threadIdx.x;
  const int z = blockIdx.z;
  A += (long long)z * aBatch;
  Bt += (long long)z * bBatch;
  const int m0 = blockIdx.y * 128, n0 = blockIdx.x * 128;

  const int w = t >> 6, l = t & 63;
  const int lr = l & 15, quad = l >> 4;
  const int wm = (w >> 1) * 64, wn = (w & 1) * 64;

  const floatx4 fz = {0.f, 0.f, 0.f, 0.f};
  floatx4 acc[4][4];
#pragma unroll
  for (int i = 0; i < 4; i++)
#pragma unroll
    for (int j = 0; j < 4; j++) acc[i][j] = fz;

  const half_t* Ap[4];
  const half_t* Bp[4];
  half_t* ldsA[4];
  half_t* ldsB[4];
#pragma unroll
  for (int s = 0; s < 4; s++) {
    int c = s * 256 + t;
    int row = c >> 3, gq = (c & 7) ^ ((c >> 3) & 7);
    Ap[s] = A + (long long)(m0 + row) * lda + gq * 8;
    Bp[s] = Bt + (long long)(n0 + row) * ldb + gq * 8;
    ldsA[s] = &As[(s * 256 + w * 64) * 8];
    ldsB[s] = &Bs[(s * 256 + w * 64) * 8];
  }

  const int p0 = quad ^ (lr & 7);
  const int p1 = (quad + 4) ^ (lr & 7);
  const int arow = (wm + lr) * 64, brow = (wn + lr) * 64;

  for (int kb = 0; kb < K; kb += 64) {
    __syncthreads();
#pragma unroll
    for (int s = 0; s < 4; s++) {
      gload16(Ap[s] + kb, ldsA[s]);
      gload16(Bp[s] + kb, ldsB[s]);
    }
    __syncthreads();
#pragma unroll
    for (int s = 0; s < 2; s++) {
      const int pp = s ? p1 : p0;
      short8 af[4], bfg[4];
#pragma unroll
      for (int j = 0; j < 4; j++) bfg[j] = *(const short8*)&Bs[brow + j * 1024 + pp * 8];
#pragma unroll
      for (int i = 0; i < 4; i++) af[i] = *(const short8*)&As[arow + i * 1024 + pp * 8];
#pragma unroll
      for (int i = 0; i < 4; i++)
#pragma unroll
        for (int j = 0; j < 4; j++)
          acc[i][j] = __builtin_amdgcn_mfma_f32_16x16x32_f16(af[i], bfg[j], acc[i][j], 0, 0, 0);
    }
  }

#pragma unroll
  for (int i = 0; i < 4; i++) {
#pragma unroll
    for (int j = 0; j < 4; j++) {
#pragma unroll
      for (int r = 0; r < 4; r++) {
        int grow = m0 + wm + i * 16 + quad * 4 + r;
        int gcol = n0 + wn + j * 16 + lr;
        float v = acc[i][j][r];
        if (MODE == EP_F32) {
          float* C = (float*)Cout + (long long)z * cBatch;
          C[(long long)grow * ldc + gcol] = v;
        } else if (MODE == EP_QK) {
          int sel = gcol >> 10;
          int ucol = gcol & 1023;
          half_t h = (half_t)v;
          if (sel == 0) {
            half_t* pq = (half_t*)Cout + (long long)grow * KCAT;
            pq[ucol] = h;
            pq[ucol + 1024] = (half_t)(v - (float)h);
          } else {
            half_t* pk = CoutK + (long long)grow * KCAT;
            pk[ucol] = h;
            pk[ucol + 1024] = h;
          }
        } else {  // EP_VT
          half_t* C = (half_t*)Cout;
          int b = grow >> 11, s = grow & 2047;
          C[((long long)b * 1024 + gcol) * 2048 + s] = (half_t)v;
        }
      }
    }
  }
}

// ---------- new 256x256 GEMM, 4-phase counted-vmcnt schedule ----------
// 8 waves (2M x 4N), per-wave 128x64 output = acc[8][4] frags of 16x16x32.
// LDS per matrix: [dbuf:2][khalf:2][256 rows][32 halves] = 64 KiB; total 128 KiB.
// Swizzle (both sides, involution): 16B chunk q at row r lives at q ^ ((r>>1)&3).
// Phases per K-tile t (buf = t&1): P0 k0/M0-3+B0, P1 k0/M4-7 (B regs reused),
// P2 k1/M0-3+B1, P3 k1/M4-7. Stage issues (ledger-verified WAR/RAW):
//   P0 -> (t+1).A-kh1 [slot free since (t-1).P3-end barrier]
//   P1 -> (t+2).B-kh0 [free since t.P0-end]   P2 -> (t+2).A-kh0 [free t.P1-end]
//   P3 -> (t+2).B-kh1 [free t.P2-end], then vmcnt(6): leaves exactly the three
//   tile-(t+2) half-tiles in flight; everything tile t+1 reads is visible.
template <int MODE>
__global__ __launch_bounds__(512, 2) void k_gemm256(
    const half_t* __restrict__ A, long long aBatch, int lda,
    const half_t* __restrict__ Bt, long long bBatch, int ldb,
    void* __restrict__ Cout, long long cBatch, int ldc, int K,
    half_t* __restrict__ CoutK) {
  __shared__ __align__(16) half_t As[32768];  // [2][2][256*32]
  __shared__ __align__(16) half_t Bs[32768];
  const int tid = threadIdx.x;
  const int z = blockIdx.z;
  A += (long long)z * aBatch;
  Bt += (long long)z * bBatch;
  const int m0 = blockIdx.y * 256, n0 = blockIdx.x * 256;
  const int w = tid >> 6, l = tid & 63;
  const int lr = l & 15, quad = l >> 4;
  const int wm = w >> 2, wn = w & 3;

  const floatx4 fz = {0.f, 0.f, 0.f, 0.f};
  floatx4 acc[8][4];
#pragma unroll
  for (int i = 0; i < 8; i++)
#pragma unroll
    for (int j = 0; j < 4; j++) acc[i][j] = fz;

  // staging: chunk c in [0,1024) per k-half: row=c>>2, phys=c&3,
  // global chunk gq = (c&3)^((c>>3)&3). Thread stages c = tid and 512+tid
  // (same gq, row+128). Source addr pre-swizzled; LDS dest linear (rule #21).
  const int r0 = tid >> 2;
  const int gq0 = (tid & 3) ^ ((tid >> 3) & 3);
  const half_t* aS0 = A + (long long)(m0 + r0) * lda + gq0 * 8;
  const half_t* aS1 = aS0 + (long long)128 * lda;
  const half_t* bS0 = Bt + (long long)(n0 + r0) * ldb + gq0 * 8;
  const half_t* bS1 = bS0 + (long long)128 * ldb;
  const int wso = w << 9;  // wave-uniform LDS chunk base (w*64 chunks * 8 halves)

  // frag read: row = Rbase + lr, phys chunk = quad ^ ((lr>>1)&3) (Rbase/2 % 4 == 0)
  const int swz = (quad ^ ((lr >> 1) & 3)) << 3;
  const int aBase = wm * 4096 + lr * 32 + swz;  // + i*512 + kh*8192 + buf*16384
  const int bBase = wn * 2048 + lr * 32 + swz;  // + j*512
  const int NT = K >> 6;

#define SA(BUF, KH, KOFF) do { half_t* d_ = &As[(BUF) * 16384 + (KH) * 8192 + wso]; \
    gload16(aS0 + (KOFF), d_); gload16(aS1 + (KOFF), d_ + 4096); } while (0)
#define SB(BUF, KH, KOFF) do { half_t* d_ = &Bs[(BUF) * 16384 + (KH) * 8192 + wso]; \
    gload16(bS0 + (KOFF), d_); gload16(bS1 + (KOFF), d_ + 4096); } while (0)
#define LDA4(OFF) { const half_t* ap_ = &As[(OFF)]; \
    af0 = *(const short8*)(ap_); af1 = *(const short8*)(ap_ + 512); \
    af2 = *(const short8*)(ap_ + 1024); af3 = *(const short8*)(ap_ + 1536); }
#define LDB4(OFF) { const half_t* bp_ = &Bs[(OFF)]; \
    bf0 = *(const short8*)(bp_); bf1 = *(const short8*)(bp_ + 512); \
    bf2 = *(const short8*)(bp_ + 1024); bf3 = *(const short8*)(bp_ + 1536); }
#define MFMA16(I0) do { \
    acc[(I0) + 0][0] = __builtin_amdgcn_mfma_f32_16x16x32_f16(af0, bf0, acc[(I0) + 0][0], 0, 0, 0); \
    acc[(I0) + 0][1] = __builtin_amdgcn_mfma_f32_16x16x32_f16(af0, bf1, acc[(I0) + 0][1], 0, 0, 0); \
    acc[(I0) + 0][2] = __builtin_amdgcn_mfma_f32_16x16x32_f16(af0, bf2, acc[(I0) + 0][2], 0, 0, 0); \
    acc[(I0) + 0][3] = __builtin_amdgcn_mfma_f32_16x16x32_f16(af0, bf3, acc[(I0) + 0][3], 0, 0, 0); \
    acc[(I0) + 1][0] = __builtin_amdgcn_mfma_f32_16x16x32_f16(af1, bf0, acc[(I0) + 1][0], 0, 0, 0); \
    acc[(I0) + 1][1] = __builtin_amdgcn_mfma_f32_16x16x32_f16(af1, bf1, acc[(I0) + 1][1], 0, 0, 0); \
    acc[(I0) + 1][2] = __builtin_amdgcn_mfma_f32_16x16x32_f16(af1, bf2, acc[(I0) + 1][2], 0, 0, 0); \
    acc[(I0) + 1][3] = __builtin_amdgcn_mfma_f32_16x16x32_f16(af1, bf3, acc[(I0) + 1][3], 0, 0, 0); \
    acc[(I0) + 2][0] = __builtin_amdgcn_mfma_f32_16x16x32_f16(af2, bf0, acc[(I0) + 2][0], 0, 0, 0); \
    acc[(I0) + 2][1] = __builtin_amdgcn_mfma_f32_16x16x32_f16(af2, bf1, acc[(I0) + 2][1], 0, 0, 0); \
    acc[(I0) + 2][2] = __builtin_amdgcn_mfma_f32_16x16x32_f16(af2, bf2, acc[(I0) + 2][2], 0, 0, 0); \
    acc[(I0) + 2][3] = __builtin_amdgcn_mfma_f32_16x16x32_f16(af2, bf3, acc[(I0) + 2][3], 0, 0, 0); \
    acc[(I0) + 3][0] = __builtin_amdgcn_mfma_f32_16x16x32_f16(af3, bf0, acc[(I0) + 3][0], 0, 0, 0); \
    acc[(I0) + 3][1] = __builtin_amdgcn_mfma_f32_16x16x32_f16(af3, bf1, acc[(I0) + 3][1], 0, 0, 0); \
    acc[(I0) + 3][2] = __builtin_amdgcn_mfma_f32_16x16x32_f16(af3, bf2, acc[(I0) + 3][2], 0, 0, 0); \
    acc[(I0) + 3][3] = __builtin_amdgcn_mfma_f32_16x16x32_f16(af3, bf3, acc[(I0) + 3][3], 0, 0, 0); \
  } while (0)

  // prologue: tile0 fully + tile1 {B-kh0, A-kh0, B-kh1}; last 3 stay in flight
  SB(0, 0, 0); SA(0, 0, 0); SB(0, 1, 32); SA(0, 1, 32);
  SB(1, 0, 64); SA(1, 0, 64); SB(1, 1, 96);
  VM6();
  BAR();

  for (int t = 0; t < NT; ++t) {
    const int buf = t & 1, nbuf = buf ^ 1;
    const int ab = buf * 16384;
    const int kb = t * 64;
    short8 af0, af1, af2, af3, bf0, bf1, bf2, bf3;

    // ---- P0: k-half0, M0-3 (+ B k-half0) ----
    LDA4(ab + aBase);
    LDB4(ab + bBase);
    if (t + 1 < NT) SA(nbuf, 1, kb + 96);  // (t+1).A-kh1
    BAR(); LGKM0();
    __builtin_amdgcn_s_setprio(1); MFMA16(0); __builtin_amdgcn_s_setprio(0);
    BAR();

    // ---- P1: k-half0, M4-7 (B regs reused) ----
    LDA4(ab + aBase + 2048);
    if (t + 2 < NT) SB(buf, 0, kb + 128);  // (t+2).B-kh0
    BAR(); LGKM0();
    __builtin_amdgcn_s_setprio(1); MFMA16(4); __builtin_amdgcn_s_setprio(0);
    BAR();

    // ---- P2: k-half1, M0-3 (+ B k-half1) ----
    LDA4(ab + 8192 + aBase);
    LDB4(ab + 8192 + bBase);
    if (t + 2 < NT) SA(buf, 0, kb + 128);  // (t+2).A-kh0
    BAR(); LGKM0();
    __builtin_amdgcn_s_setprio(1); MFMA16(0); __builtin_amdgcn_s_setprio(0);
    BAR();

    // ---- P3: k-half1, M4-7 ----
    LDA4(ab + 8192 + aBase + 2048);
    if (t + 2 < NT) SB(buf, 1, kb + 160);  // (t+2).B-kh1
    if (t < NT - 2) { VM6(); } else if (t == NT - 2) { VM0(); }  // tail drains
    BAR(); LGKM0();
    __builtin_amdgcn_s_setprio(1); MFMA16(4); __builtin_amdgcn_s_setprio(0);
    BAR();
  }

#pragma unroll
  for (int i = 0; i < 8; i++) {
#pragma unroll
    for (int j = 0; j < 4; j++) {
#pragma unroll
      for (int r = 0; r < 4; r++) {
        int grow = m0 + wm * 128 + i * 16 + quad * 4 + r;
        int gcol = n0 + wn * 64 + j * 16 + lr;
        float v = acc[i][j][r];
        if (MODE == EP_F32) {
          float* C = (float*)Cout + (long long)z * cBatch;
          C[(long long)grow * ldc + gcol] = v;
        } else {  // EP_QK
          int sel = gcol >> 10;
          int ucol = gcol & 1023;
          half_t h = (half_t)v;
          if (sel == 0) {
            half_t* pq = (half_t*)Cout + (long long)grow * KCAT;
            pq[ucol] = h;
            pq[ucol + 1024] = (half_t)(v - (float)h);
          } else {
            half_t* pk = CoutK + (long long)grow * KCAT;
            pk[ucol] = h;
            pk[ucol + 1024] = h;
          }
        }
      }
    }
  }
#undef SA
#undef SB
#undef LDA4
#undef LDB4
#undef MFMA16
}

// ---------- softmax, in place: S row (fp32[2048]) -> P row (fp16[2048]) ----------
__global__ __launch_bounds__(256) void k_softmax(float* __restrict__ Sbuf) {
  long long row = blockIdx.x;  // 0..8191
  float* p = Sbuf + row * 2048;
  int t = threadIdx.x;
  float4 v0 = ((const float4*)p)[t];
  float4 v1 = ((const float4*)p)[t + 256];
  float m = fmaxf(fmaxf(fmaxf(v0.x, v0.y), fmaxf(v0.z, v0.w)),
                  fmaxf(fmaxf(v1.x, v1.y), fmaxf(v1.z, v1.w)));
  for (int off = 32; off; off >>= 1) m = fmaxf(m, __shfl_xor(m, off));
  __shared__ float red[8];
  int wv = t >> 6, ln = t & 63;
  if (ln == 0) red[wv] = m;
  __syncthreads();
  m = fmaxf(fmaxf(red[0], red[1]), fmaxf(red[2], red[3]));
  float e0 = __expf(v0.x - m), e1 = __expf(v0.y - m), e2 = __expf(v0.z - m), e3 = __expf(v0.w - m);
  float e4 = __expf(v1.x - m), e5 = __expf(v1.y - m), e6 = __expf(v1.z - m), e7 = __expf(v1.w - m);
  float s = ((e0 + e1) + (e2 + e3)) + ((e4 + e5) + (e6 + e7));
  for (int off = 32; off; off >>= 1) s += __shfl_xor(s, off);
  if (ln == 0) red[4 + wv] = s;
  __syncthreads();
  s = (red[4] + red[5]) + (red[6] + red[7]);
  float inv = 1.0f / s;
  uint2 w0, w1;
  w0.x = (unsigned)h2u((half_t)(e0 * inv)) | ((unsigned)h2u((half_t)(e1 * inv)) << 16);
  w0.y = (unsigned)h2u((half_t)(e2 * inv)) | ((unsigned)h2u((half_t)(e3 * inv)) << 16);
  w1.x = (unsigned)h2u((half_t)(e4 * inv)) | ((unsigned)h2u((half_t)(e5 * inv)) << 16);
  w1.y = (unsigned)h2u((half_t)(e6 * inv)) | ((unsigned)h2u((half_t)(e7 * inv)) << 16);
  ((uint2*)p)[t] = w0;
  ((uint2*)p)[t + 256] = w1;
}

// ---------- host launch ----------
extern "C" void kernel_launch(void* const* d_in, const int* in_sizes, int n_in,
                              void* d_out, int out_size, void* d_ws, size_t ws_size,
                              hipStream_t stream) {
  (void)in_sizes; (void)n_in; (void)out_size;
  if (ws_size < WS_NEED) return;  // output stays poisoned -> visible failure

  const float* X = (const float*)d_in[0];
  const float* Wq = (const float*)d_in[1];
  const float* Wk = (const float*)d_in[2];
  const float* Wv = (const float*)d_in[3];
  char* ws = (char*)d_ws;
  half_t* xcat = (half_t*)(ws + XCAT_OFF);
  half_t* wt = (half_t*)(ws + WT_OFF);
  float* Sbuf = (float*)(ws + S_OFF);
  half_t* qcat = (half_t*)(ws + QCAT_OFF);
  half_t* kcat = (half_t*)(ws + KCAT_OFF);
  half_t* vt = (half_t*)(ws + VT_OFF);
  float* out = (float*)d_out;

  // 1. split X and W (fp16)
  k_split_x<<<dim3(MX * 1024 / 256), dim3(256), 0, stream>>>(X, xcat);
  k_split_wt<<<dim3(16, 16, 3), dim3(256), 0, stream>>>(Wq, Wk, Wv, wt);

  // 2a. fused QK projection: M=8192, N=2048 (Wq|Wk rows), K=2048 (2-term)
  //     256^2 tiles -> 8x32 = 256 blocks = 1/CU.
  k_gemm256<EP_QK><<<dim3(8, 32, 1), dim3(512), 0, stream>>>(
      xcat, 0LL, KCAT, wt, 0LL, KCAT, qcat, 0LL, 0, KCAT, kcat);

  // 2b. V projection: M=8192, N=1024, K=1024 (1-term) -- old 128^2 kernel
  k_gemm<EP_VT><<<dim3(8, 64, 1), dim3(256), 0, stream>>>(
      xcat, 0LL, KCAT, wt + 2 * 1024 * KCAT, 0LL, KCAT, vt, 0LL, 0, 1024, nullptr);

  // 3. scores S = Q K^T (fp16 2-term), fp32 out: per batch M=N=2048
  //    256^2 tiles -> 8x8x4 = 256 blocks = 1/CU.
  k_gemm256<EP_F32><<<dim3(8, 8, 4), dim3(512), 0, stream>>>(
      qcat, (long long)2048 * KCAT, KCAT, kcat, (long long)2048 * KCAT, KCAT,
      Sbuf, (long long)2048 * 2048, 2048, KCAT, nullptr);

  // 4. softmax in place (fp32 row -> fp16 row; row stride becomes 4096 halves)
  k_softmax<<<dim3(8192), dim3(256), 0, stream>>>(Sbuf);

  // 5. O = P V (plain fp16), fp32 out: per batch M=2048, N=1024, K=2048
  k_gemm<EP_F32><<<dim3(8, 16, 4), dim3(256), 0, stream>>>(
      (const half_t*)Sbuf, (long long)2048 * 4096, 4096,
      vt, (long long)1024 * 2048, 2048,
      out, (long long)2048 * 1024, 1024, 2048, nullptr);
}